// Round 12
// baseline (555.834 us; speedup 1.0000x reference)
//
#include <hip/hip_runtime.h>
#include <stdint.h>
#include <stddef.h>

#define N_NODES 20000
#define N_EDGES 320000

typedef unsigned short u16;
typedef __attribute__((ext_vector_type(8))) short bf16x8;
typedef __attribute__((ext_vector_type(8))) unsigned short u16x8;
typedef __attribute__((ext_vector_type(4))) float f32x4;

__device__ __forceinline__ float bf2f(u16 u) {
    union { unsigned int i; float f; } v; v.i = ((unsigned int)u) << 16; return v.f;
}
__device__ __forceinline__ u16 f2bf(float f) {
    union { float f; unsigned int i; } v; v.f = f;
    unsigned int x = v.i;
    unsigned int r = x + 0x7fffu + ((x >> 16) & 1u);
    return (u16)(r >> 16);
}
__device__ __forceinline__ int clampi(int v, int lo, int hi) {
    return v < lo ? lo : (v > hi ? hi : v);
}
__device__ __forceinline__ float ld1(const void* p, size_t i, int f32) {
    return f32 ? ((const float*)p)[i] : bf2f(((const u16*)p)[i]);
}

// async 16B global -> LDS (wave-uniform LDS base + lane*16; global addr per-lane)
__device__ __forceinline__ void async_ld16(void* lds, const void* g) {
    __builtin_amdgcn_global_load_lds(
        (const __attribute__((address_space(1))) unsigned int*)g,
        (__attribute__((address_space(3))) unsigned int*)lds,
        16, 0, 0);
}

// bijective chunked XCD transform: hw id -> logical id; each XCD gets a
// contiguous chunk of logical ids. VERIFIED (r7 bisect): passes, FETCH 84->23MB.
__device__ __forceinline__ int xcd_chunk(int b, int nwg) {
    int x = b & 7, idx = b >> 3;
    int q = nwg >> 3, r = nwg & 7;
    return ((x < r) ? (x * (q + 1)) : (r * (q + 1) + (x - r) * q)) + idx;
}

__global__ void marker_kernel(u16* out, u16 code) { out[threadIdx.x] = code; }

// dtype sniff + sentinel. diag[0]=sentinel, diag[1]=fp32 flag, diag[2]=const 0
__global__ void detect_kernel(const void* feat, int* diag) {
    int lane = threadIdx.x;
    int weird = 0;
    const u16* p = (const u16*)feat;
    for (int i = lane; i < 512; i += 64) {
        float v = bf2f(p[i]);
        float a = fabsf(v);
        if (!(a <= 1e4f) || (a != 0.f && a < 1e-6f)) weird++;
    }
#pragma unroll
    for (int off = 32; off > 0; off >>= 1) weird += __shfl_xor(weird, off, 64);
    if (lane == 0) { diag[0] = 123456; diag[1] = (weird > 51) ? 1 : 0; diag[2] = 0; }
}

// rpe collapse: out[p*4+h] = sum_d Wrpe[p][h*64+d]; out[12+h] = sum_d brpe[h*64+d]
__global__ void rpe_sums_kernel(const void* __restrict__ Wrpe, const void* __restrict__ brpe,
                                float* __restrict__ out, const int* __restrict__ dflag) {
    int f32 = dflag[0];
    int t = threadIdx.x;
    if (t < 12) {
        int p = t >> 2, h = t & 3;
        float s = 0.f;
        for (int d = 0; d < 64; ++d) s += ld1(Wrpe, p * 256 + h * 64 + d, f32);
        out[t] = s;
    } else if (t < 16) {
        int h = t - 12;
        float s = 0.f;
        for (int d = 0; d < 64; ++d) s += ld1(brpe, h * 64 + d, f32);
        out[12 + h] = s;
    }
}

// proj[n*4+h] = sum_p coord[n,p] * rpe_sums[p*4+h]
__global__ __launch_bounds__(256) void coordproj_kernel(const void* __restrict__ coord,
                                                        const int* __restrict__ dflag,
                                                        const float* __restrict__ rs,
                                                        float* __restrict__ proj, int n) {
    int i = blockIdx.x * 256 + threadIdx.x;
    if (i >= n * 4) return;
    int f32 = dflag[0];
    int node = i >> 2, h = i & 3;
    float s = ld1(coord, (size_t)node * 3 + 0, f32) * rs[0 * 4 + h]
            + ld1(coord, (size_t)node * 3 + 1, f32) * rs[1 * 4 + h]
            + ld1(coord, (size_t)node * 3 + 2, f32) * rs[2 * 4 + h];
    proj[i] = s;
}

// Wt[n*K + k] = bf16(W[k*N + n])  (weight transpose + convert)
__global__ __launch_bounds__(256) void transpose_w_kernel(const void* __restrict__ W,
                                                          const int* __restrict__ dflag,
                                                          u16* __restrict__ Wt, int K, int N) {
    int f32 = dflag[0];
    int i = blockIdx.x * 256 + threadIdx.x;
    if (i >= K * N) return;
    int n = i / K, k = i - n * K;
    Wt[i] = f2bf(ld1(W, (size_t)k * N + n, f32));
}

// feat (f32 or bf16) -> bf16, both sets, vectorized 8/thread
__global__ __launch_bounds__(256) void tobf16_kernel(
        const void* __restrict__ a, const void* __restrict__ b,
        const int* __restrict__ dflag, u16* __restrict__ oa, u16* __restrict__ ob) {
    const int PER = N_NODES * 256 / 8;   // 640000
    int idx = blockIdx.x * 256 + threadIdx.x;
    if (idx >= 2 * PER) return;
    int set = idx >= PER;
    int j = (idx - set * PER) * 8;
    const void* src = set ? b : a;
    u16* dst = set ? ob : oa;
    int f32 = dflag[0];
    u16x8 o;
    if (f32) {
        const float* p = (const float*)src + j;
        float4 u0 = *(const float4*)p, u1 = *(const float4*)(p + 4);
        o[0] = f2bf(u0.x); o[1] = f2bf(u0.y); o[2] = f2bf(u0.z); o[3] = f2bf(u0.w);
        o[4] = f2bf(u1.x); o[5] = f2bf(u1.y); o[6] = f2bf(u1.z); o[7] = f2bf(u1.w);
    } else {
        o = *(const u16x8*)((const u16*)src + j);
    }
    *(u16x8*)(dst + j) = o;
}

// ---------------------------------------------------------------- CSR build
// r12: split-copy atomics. Copy index = gi*2 + h with h=(b>>2)&1; a block's
// copy is touched only by blocks with b%8 == gi+4h (one XCD residue class
// under the observed round-robin b%8->XCD mapping) -> no cross-XCD line
// ping-pong on deg. rank stores (h<<15)|pos; per-half degree < 32768 for
// non-adversarial graphs (same overflow class as the prior u16 rank).
__global__ __launch_bounds__(256) void count_kernel(
        const int* __restrict__ g0, const int* __restrict__ g1,
        const int* __restrict__ g2, const int* __restrict__ g3,
        int* __restrict__ deg, u16* __restrict__ rank) {
    int b = blockIdx.x;
    int gi = b & 3;
    int h = (b >> 2) & 1;
    int e = (b >> 2) * 256 + (int)threadIdx.x;
    if (e >= N_EDGES) return;
    const int* g = (gi == 0) ? g0 : (gi == 1) ? g1 : (gi == 2) ? g2 : g3;
    int dst = clampi(g[e], 0, N_NODES - 1);
    int pos = atomicAdd(&deg[(gi * 2 + h) * N_NODES + dst], 1);
    pos = pos & 0x7fff;
    rank[(size_t)gi * N_EDGES + e] = (u16)((h << 15) | pos);
}

// scan: rowptr from deg0+deg1 prefix; deg copies left INTACT (fill reads deg0).
__global__ __launch_bounds__(256) void scan_kernel(const int* __restrict__ cur,
                                                   int* __restrict__ rowptr) {
    int g = blockIdx.x;
    int tid = threadIdx.x;
    __shared__ int buf[256];
    const int* d0 = cur + (g * 2 + 0) * N_NODES;
    const int* d1 = cur + (g * 2 + 1) * N_NODES;
    int* rp = rowptr + g * (N_NODES + 1);
    const int CH = (N_NODES + 255) / 256;
    int lo = tid * CH;
    int hi = lo + CH; if (hi > N_NODES) hi = N_NODES;
    int s = 0;
    for (int i = lo; i < hi; ++i) s += d0[i] + d1[i];
    buf[tid] = s;
    __syncthreads();
    for (int off = 1; off < 256; off <<= 1) {
        int x = (tid >= off) ? buf[tid - off] : 0;
        __syncthreads();
        buf[tid] += x;
        __syncthreads();
    }
    int run = (tid == 0) ? 0 : buf[tid - 1];
    for (int i = lo; i < hi; ++i) {
        rp[i] = run;
        run += d0[i] + d1[i];
    }
    if (tid == 255) rp[N_NODES] = buf[255];
}

// fill: NO atomics — pos = rowptr[dst] + (h ? deg0[dst] : 0) + rank. u16 col.
__global__ __launch_bounds__(256) void fill_kernel(
        const int* __restrict__ g0, const int* __restrict__ g1,
        const int* __restrict__ g2, const int* __restrict__ g3,
        const int* __restrict__ rowptr, const int* __restrict__ cur,
        const u16* __restrict__ rank, u16* __restrict__ col) {
    int b = blockIdx.x;
    int gi = b & 3;
    int e = (b >> 2) * 256 + (int)threadIdx.x;
    if (e >= N_EDGES) return;
    const int* g = (gi == 0) ? g0 : (gi == 1) ? g1 : (gi == 2) ? g2 : g3;
    int dst = clampi(g[e], 0, N_NODES - 1);
    int src = clampi(g[N_EDGES + e], 0, N_NODES - 1);
    u16 rk = rank[(size_t)gi * N_EDGES + e];
    int h = rk >> 15, r = rk & 0x7fff;
    int base = h ? cur[(gi * 2 + 0) * N_NODES + dst] : 0;
    int pos = rowptr[gi * (N_NODES + 1) + dst] + base + r;
    if (pos >= 0 && pos < N_EDGES)
        col[(size_t)gi * N_EDGES + pos] = (u16)src;
}

// ---------------------------------------------------------------- classic MFMA GEMM (fallback path)
__global__ __launch_bounds__(256) void gemm_mfma(
        const void* __restrict__ A, int lda, const int* __restrict__ aflag,
        const u16* __restrict__ Bt,
        const void* __restrict__ bias, size_t biasoff, const int* __restrict__ bflag,
        void* __restrict__ C, size_t coff, int ldc, const int* __restrict__ cflag,
        int M, int N, int K) {
    __shared__ __align__(16) u16 As[128 * 40];
    __shared__ __align__(16) u16 Bs[128 * 40];
    const int f32a = aflag[0], f32b = bflag[0], f32c = cflag[0];
    const int t = threadIdx.x;
    const int lane = t & 63, wv = t >> 6;
    const int wm = (wv >> 1) * 64, wn = (wv & 1) * 64;
    const int m0 = blockIdx.y * 128, n0 = blockIdx.x * 128;
    const int l15 = lane & 15, lq = lane >> 4;

    f32x4 acc[4][4];
#pragma unroll
    for (int i = 0; i < 4; ++i)
#pragma unroll
        for (int j = 0; j < 4; ++j) acc[i][j] = (f32x4){0.f, 0.f, 0.f, 0.f};

    const int sr = t >> 1, skc = (t & 1) * 16;

    for (int k0 = 0; k0 < K; k0 += 32) {
        __syncthreads();
        {
            __align__(16) u16 tmp[16];
            int gm = m0 + sr;
            if (gm < M) {
                if (f32a) {
                    const float* ap = (const float*)A + (size_t)gm * lda + k0 + skc;
#pragma unroll
                    for (int i = 0; i < 16; i += 4) {
                        float4 u = *(const float4*)(ap + i);
                        tmp[i] = f2bf(u.x); tmp[i + 1] = f2bf(u.y);
                        tmp[i + 2] = f2bf(u.z); tmp[i + 3] = f2bf(u.w);
                    }
                } else {
                    const u16* ap = (const u16*)A + (size_t)gm * lda + k0 + skc;
                    *(u16x8*)&tmp[0] = *(const u16x8*)ap;
                    *(u16x8*)&tmp[8] = *(const u16x8*)(ap + 8);
                }
            } else {
#pragma unroll
                for (int i = 0; i < 16; ++i) tmp[i] = 0;
            }
            *(u16x8*)&As[sr * 40 + skc] = *(u16x8*)&tmp[0];
            *(u16x8*)&As[sr * 40 + skc + 8] = *(u16x8*)&tmp[8];
        }
        {
            const u16* bp = Bt + (size_t)(n0 + sr) * K + k0 + skc;
            u16x8 b0 = *(const u16x8*)bp;
            u16x8 b1 = *(const u16x8*)(bp + 8);
            *(u16x8*)&Bs[sr * 40 + skc] = b0;
            *(u16x8*)&Bs[sr * 40 + skc + 8] = b1;
        }
        __syncthreads();
        bf16x8 af[4], bfr[4];
#pragma unroll
        for (int mt = 0; mt < 4; ++mt)
            af[mt] = *(const bf16x8*)&As[(wm + mt * 16 + l15) * 40 + lq * 8];
#pragma unroll
        for (int nt = 0; nt < 4; ++nt)
            bfr[nt] = *(const bf16x8*)&Bs[(wn + nt * 16 + l15) * 40 + lq * 8];
#pragma unroll
        for (int mt = 0; mt < 4; ++mt)
#pragma unroll
            for (int nt = 0; nt < 4; ++nt)
                acc[mt][nt] = __builtin_amdgcn_mfma_f32_16x16x32_bf16(af[mt], bfr[nt], acc[mt][nt], 0, 0, 0);
    }
#pragma unroll
    for (int mt = 0; mt < 4; ++mt) {
#pragma unroll
        for (int nt = 0; nt < 4; ++nt) {
            int gn = n0 + wn + nt * 16 + l15;
            float bb = ld1(bias, biasoff + gn, f32b);
#pragma unroll
            for (int r = 0; r < 4; ++r) {
                int gm = m0 + wm + mt * 16 + lq * 4 + r;
                if (gm < M) {
                    float v = acc[mt][nt][r] + bb;
                    size_t ic = coff + (size_t)gm * ldc + gn;
                    if (f32c) ((float*)C)[ic] = v;
                    else      ((u16*)C)[ic] = f2bf(v);
                }
            }
        }
    }
}

// ---------------------------------------------------------------- pipelined dual GEMM (m97 structure)
// r11-verified: BK=64, pre-swizzled global source + swizzled read (linear LDS
// dest for global_load_lds), 32KB LDS + (256,4) -> 4 blocks/CU. XCD map
// r7-verified; swizzled LDS C-stage epilogue r10-verified.
__global__ __launch_bounds__(256, 4) void gemm_pipe(
        const u16* __restrict__ A1, const u16* __restrict__ A2, int K,
        const u16* __restrict__ Bt1, const u16* __restrict__ Bt2,
        const void* __restrict__ bias1, const void* __restrict__ bias2,
        const int* __restrict__ bflag,
        void* __restrict__ C, size_t coff1, size_t coff2, int ldc,
        const int* __restrict__ cflag,
        int M, int nr, int nc) {
    __shared__ __align__(16) u16 S[16384];   // As(16KB) | Bs(16KB), reused as C-stage
    u16* As = S;
    u16* Bs = S + 8192;
    const int f32b = bflag[0], f32c = cflag[0];
    const int t = threadIdx.x;
    const int half = nr * nc;
    const int nwg = 2 * half;
    int b = xcd_chunk(blockIdx.x, nwg);
    const int set = (b >= half) ? 1 : 0;
    b -= set * half;
    const int c = b % nc, r = b / nc;
    const int m0 = r * 128, n0 = c * 128;
    const u16* A   = set ? A2 : A1;
    const u16* Bt  = set ? Bt2 : Bt1;
    const void* bias = set ? bias2 : bias1;
    const size_t coff = set ? coff2 : coff1;

    const int lane = t & 63, wv = t >> 6;
    const int wm = (wv >> 1) * 64, wn = (wv & 1) * 64;
    const int l15 = lane & 15, lq = lane >> 4;

    // staging: wave wv stages LDS rows [wv*32, wv*32+32) x 64 cols in 4+4 instrs.
    const int srow8 = lane >> 3;             // 0..7 (== row&7 of staged row)
    const int sgsw  = ((lane & 7) ^ srow8) * 8;  // swizzled source granule, u16 units
    const u16* agp[4];
    const u16* bgp[4];
    u16 *lap[4], *lbp[4];
#pragma unroll
    for (int i = 0; i < 4; ++i) {
        int ra = m0 + wv * 32 + i * 8 + srow8; if (ra > M - 1) ra = M - 1;
        int rb = n0 + wv * 32 + i * 8 + srow8;
        agp[i] = A  + (size_t)ra * K + sgsw;
        bgp[i] = Bt + (size_t)rb * K + sgsw;
        lap[i] = &As[(wv * 32 + i * 8) * 64];
        lbp[i] = &Bs[(wv * 32 + i * 8) * 64];
    }
    const int l7 = l15 & 7;                  // row&7 of fragment rows

    f32x4 acc[4][4];
#pragma unroll
    for (int i = 0; i < 4; ++i)
#pragma unroll
        for (int j = 0; j < 4; ++j) acc[i][j] = (f32x4){0.f, 0.f, 0.f, 0.f};

    for (int k0 = 0; k0 < K; k0 += 64) {
        __syncthreads();                       // protect prev iteration's readers
#pragma unroll
        for (int i = 0; i < 4; ++i) async_ld16(lap[i], agp[i] + k0);
#pragma unroll
        for (int i = 0; i < 4; ++i) async_ld16(lbp[i], bgp[i] + k0);
        __syncthreads();                       // vmcnt(0) drain -> LDS valid
#pragma unroll
        for (int h2 = 0; h2 < 2; ++h2) {
            const int gq = lq + h2 * 4;        // wanted granule 0..7
            bf16x8 af[4], bfr[4];
#pragma unroll
            for (int mt = 0; mt < 4; ++mt)
                af[mt] = *(const bf16x8*)&As[(wm + mt * 16 + l15) * 64 + ((gq ^ l7) << 3)];
#pragma unroll
            for (int nt = 0; nt < 4; ++nt)
                bfr[nt] = *(const bf16x8*)&Bs[(wn + nt * 16 + l15) * 64 + ((gq ^ l7) << 3)];
#pragma unroll
            for (int mt = 0; mt < 4; ++mt)
#pragma unroll
                for (int nt = 0; nt < 4; ++nt)
                    acc[mt][nt] = __builtin_amdgcn_mfma_f32_16x16x32_bf16(
                        bfr[nt], af[mt], acc[mt][nt], 0, 0, 0);
        }
    }

    // ---- epilogue via LDS stage -> full-line stores (r10-verified, swizzled)
    if (!f32c) {
        u16* Cs = S;                           // 64 rows x 128 cols bf16 = 16 KB
#pragma unroll
        for (int p = 0; p < 2; ++p) {
            __syncthreads();
            if ((wv >> 1) == p) {
#pragma unroll
                for (int nt = 0; nt < 4; ++nt) {
                    int lc = wn + nt * 16 + lq * 4;
                    int gn0 = n0 + lc;
                    float b0 = ld1(bias, gn0 + 0, f32b);
                    float b1 = ld1(bias, gn0 + 1, f32b);
                    float b2 = ld1(bias, gn0 + 2, f32b);
                    float b3 = ld1(bias, gn0 + 3, f32b);
#pragma unroll
                    for (int mt = 0; mt < 4; ++mt) {
                        ushort4 o;
                        o.x = f2bf(acc[mt][nt][0] + b0);
                        o.y = f2bf(acc[mt][nt][1] + b1);
                        o.z = f2bf(acc[mt][nt][2] + b2);
                        o.w = f2bf(acc[mt][nt][3] + b3);
                        // swizzled deposit: row&15 == l15 for writers
                        *(ushort4*)&Cs[(mt * 16 + l15) * 128 + (lc ^ (l15 << 3))] = o;
                    }
                }
            }
            __syncthreads();
#pragma unroll
            for (int it = 0; it < 4; ++it) {   // 64 rows x 16 chunks of 16B
                int idx = it * 256 + t;
                int row = idx >> 4, ch = idx & 15;
                int gm = m0 + p * 64 + row;
                if (gm < M)
                    *(u16x8*)((u16*)C + coff + (size_t)gm * ldc + n0 + ch * 8) =
                        *(const u16x8*)&Cs[row * 128 + ((ch * 8) ^ ((row & 15) << 3))];
            }
        }
    } else {
        float* Cs = (float*)S;                 // 32 rows x 128 cols f32 = 16 KB
#pragma unroll
        for (int p = 0; p < 4; ++p) {
            __syncthreads();
            if ((wv >> 1) == (p >> 1)) {
                int mtb = (p & 1) * 2;
#pragma unroll
                for (int nt = 0; nt < 4; ++nt) {
                    int lc = wn + nt * 16 + lq * 4;
                    int gn0 = n0 + lc;
                    float b0 = ld1(bias, gn0 + 0, f32b);
                    float b1 = ld1(bias, gn0 + 1, f32b);
                    float b2 = ld1(bias, gn0 + 2, f32b);
                    float b3 = ld1(bias, gn0 + 3, f32b);
#pragma unroll
                    for (int mi = 0; mi < 2; ++mi) {
                        int mt = mtb + mi;
                        f32x4 o;
                        o[0] = acc[mt][nt][0] + b0;
                        o[1] = acc[mt][nt][1] + b1;
                        o[2] = acc[mt][nt][2] + b2;
                        o[3] = acc[mt][nt][3] + b3;
                        *(f32x4*)&Cs[(mi * 16 + l15) * 128 + lc] = o;
                    }
                }
            }
            __syncthreads();
#pragma unroll
            for (int it = 0; it < 4; ++it) {   // 32 rows x 32 chunks of 16B
                int idx = it * 256 + t;
                int row = idx >> 5, ch = idx & 31;
                int gm = m0 + p * 32 + row;
                if (gm < M)
                    *(float4*)((float*)C + coff + (size_t)gm * ldc + n0 + ch * 4) =
                        *(const float4*)&Cs[row * 128 + ch * 4];
            }
        }
    }
}

// ---------------------------------------------------------------- edge attention v3
// wave per dst node; lane = h*16+j; lane owns d = j*4..j*4+3 of head h. ldt = row stride.
__global__ __launch_bounds__(256) void attn3_kernel(
        const u16* __restrict__ Q, const u16* __restrict__ Kp, const u16* __restrict__ Vp,
        const int* __restrict__ rowptr, const u16* __restrict__ col,
        const float* __restrict__ projN, const float* __restrict__ projS,
        const float* __restrict__ rb, int use_rpe,
        u16* __restrict__ outp, int ldt) {
    int lane = threadIdx.x & 63;
    int node = blockIdx.x * 4 + (threadIdx.x >> 6);
    if (node >= N_NODES) return;
    int h = lane >> 4;
    int off = h * 64 + (lane & 15) * 4;

    ushort4 qu = *(const ushort4*)(Q + (size_t)node * ldt + off);
    float q0 = bf2f(qu.x), q1 = bf2f(qu.y), q2 = bf2f(qu.z), q3 = bf2f(qu.w);
    float base = use_rpe ? (projN[node * 4 + h] + rb[h]) : 0.f;

    float m = -1e30f, l = 0.f, a0 = 0.f, a1 = 0.f, a2 = 0.f, a3 = 0.f;
    int e0 = rowptr[node], e1 = rowptr[node + 1];
    e0 = clampi(e0, 0, N_EDGES);
    e1 = clampi(e1, e0, N_EDGES);
    int e = e0;
    for (; e + 4 <= e1; e += 4) {
        int s0 = clampi((int)col[e + 0], 0, N_NODES - 1);
        int s1 = clampi((int)col[e + 1], 0, N_NODES - 1);
        int s2 = clampi((int)col[e + 2], 0, N_NODES - 1);
        int s3 = clampi((int)col[e + 3], 0, N_NODES - 1);
        ushort4 k0 = *(const ushort4*)(Kp + (size_t)s0 * ldt + off);
        ushort4 k1 = *(const ushort4*)(Kp + (size_t)s1 * ldt + off);
        ushort4 k2 = *(const ushort4*)(Kp + (size_t)s2 * ldt + off);
        ushort4 k3 = *(const ushort4*)(Kp + (size_t)s3 * ldt + off);
        ushort4 v0 = *(const ushort4*)(Vp + (size_t)s0 * ldt + off);
        ushort4 v1 = *(const ushort4*)(Vp + (size_t)s1 * ldt + off);
        ushort4 v2 = *(const ushort4*)(Vp + (size_t)s2 * ldt + off);
        ushort4 v3 = *(const ushort4*)(Vp + (size_t)s3 * ldt + off);
        float t0 = q0 * bf2f(k0.x) + q1 * bf2f(k0.y) + q2 * bf2f(k0.z) + q3 * bf2f(k0.w);
        float t1 = q0 * bf2f(k1.x) + q1 * bf2f(k1.y) + q2 * bf2f(k1.z) + q3 * bf2f(k1.w);
        float t2 = q0 * bf2f(k2.x) + q1 * bf2f(k2.y) + q2 * bf2f(k2.z) + q3 * bf2f(k2.w);
        float t3 = q0 * bf2f(k3.x) + q1 * bf2f(k3.y) + q2 * bf2f(k3.z) + q3 * bf2f(k3.w);
#pragma unroll
        for (int sh = 1; sh <= 8; sh <<= 1) {
            t0 += __shfl_xor(t0, sh, 64);
            t1 += __shfl_xor(t1, sh, 64);
            t2 += __shfl_xor(t2, sh, 64);
            t3 += __shfl_xor(t3, sh, 64);
        }
        if (use_rpe) {
            t0 += base - projS[s0 * 4 + h];
            t1 += base - projS[s1 * 4 + h];
            t2 += base - projS[s2 * 4 + h];
            t3 += base - projS[s3 * 4 + h];
        }
        float mx = fmaxf(fmaxf(fmaxf(t0, t1), fmaxf(t2, t3)), m);
        float sc = __expf(m - mx);
        float p0 = __expf(t0 - mx), p1 = __expf(t1 - mx);
        float p2 = __expf(t2 - mx), p3 = __expf(t3 - mx);
        l = l * sc + (p0 + p1 + p2 + p3);
        a0 = a0 * sc + p0 * bf2f(v0.x) + p1 * bf2f(v1.x) + p2 * bf2f(v2.x) + p3 * bf2f(v3.x);
        a1 = a1 * sc + p0 * bf2f(v0.y) + p1 * bf2f(v1.y) + p2 * bf2f(v2.y) + p3 * bf2f(v3.y);
        a2 = a2 * sc + p0 * bf2f(v0.z) + p1 * bf2f(v1.z) + p2 * bf2f(v2.z) + p3 * bf2f(v3.z);
        a3 = a3 * sc + p0 * bf2f(v0.w) + p1 * bf2f(v1.w) + p2 * bf2f(v2.w) + p3 * bf2f(v3.w);
        m = mx;
    }
    for (; e < e1; ++e) {
        int src = clampi((int)col[e], 0, N_NODES - 1);
        ushort4 ku = *(const ushort4*)(Kp + (size_t)src * ldt + off);
        ushort4 vu = *(const ushort4*)(Vp + (size_t)src * ldt + off);
        float tv = q0 * bf2f(ku.x) + q1 * bf2f(ku.y) + q2 * bf2f(ku.z) + q3 * bf2f(ku.w);
        tv += __shfl_xor(tv, 1, 64);
        tv += __shfl_xor(tv, 2, 64);
        tv += __shfl_xor(tv, 4, 64);
        tv += __shfl_xor(tv, 8, 64);
        if (use_rpe) tv += base - projS[src * 4 + h];
        float mn = fmaxf(m, tv);
        float sc = __expf(m - mn), p = __expf(tv - mn);
        l = l * sc + p;
        a0 = a0 * sc + p * bf2f(vu.x);
        a1 = a1 * sc + p * bf2f(vu.y);
        a2 = a2 * sc + p * bf2f(vu.z);
        a3 = a3 * sc + p * bf2f(vu.w);
        m = mn;
    }
    float inv = l > 0.f ? 1.f / l : 0.f;
    ushort4 o;
    o.x = f2bf(a0 * inv); o.y = f2bf(a1 * inv); o.z = f2bf(a2 * inv); o.w = f2bf(a3 * inv);
    *(ushort4*)(outp + (size_t)node * 512 + off) = o;
}

// ---------------------------------------------------------------- launch
extern "C" void kernel_launch(void* const* d_in, const int* in_sizes, int n_in,
                              void* d_out, int out_size, void* d_ws, size_t ws_size,
                              hipStream_t stream) {
    const void* feat1  = d_in[0];
    const void* coord1 = d_in[1];
    const void* feat2  = d_in[2];
    const void* coord2 = d_in[3];
    const void* Wqkv1  = d_in[4];
    const void* bqkv1  = d_in[5];
    const void* Wqkv2  = d_in[6];
    const void* bqkv2  = d_in[7];
    const void* Wproj1 = d_in[8];
    const void* bproj1 = d_in[9];
    const void* Wproj2 = d_in[10];
    const void* bproj2 = d_in[11];
    const void* Wrpe   = d_in[12];
    const void* brpe   = d_in[13];
    const int* graph1  = (const int*)d_in[14];
    const int* graph2  = (const int*)d_in[15];
    const int* graph12 = (const int*)d_in[16];
    const int* graph21 = (const int*)d_in[17];
    u16* out = (u16*)d_out;

    {   // layout assertion
        static const int expect[18] = {
            N_NODES * 256, N_NODES * 3, N_NODES * 256, N_NODES * 3,
            256 * 1536, 1536, 256 * 1536, 1536,
            512 * 256, 256, 512 * 256, 256,
            3 * 256, 256,
            2 * N_EDGES, 2 * N_EDGES, 2 * N_EDGES, 2 * N_EDGES };
        bool ok = (n_in == 18) && (out_size == 2 * N_NODES * 256);
        if (ok) for (int i = 0; i < 18; ++i) if (in_sizes[i] != expect[i]) ok = false;
        if (!ok) { marker_kernel<<<1, 16, 0, stream>>>(out, 0x4496 /*~1200*/); return; }
    }

    char* w = (char*)d_ws;
    size_t off = 0;
    auto alloc = [&](size_t bytes) { void* p = w + off; off += (bytes + 255) & ~(size_t)255; return p; };
    int* rowptr  = (int*)alloc(4ull * (N_NODES + 1) * 4);
    int* cur     = (int*)alloc(8ull * N_NODES * 4);   // r12: 2 copies per graph
    u16* col     = (u16*)alloc(4ull * N_EDGES * 2);
    u16* rank    = (u16*)alloc(4ull * N_EDGES * 2);
    float* rpe_s = (float*)alloc(64);
    int* diag    = (int*)alloc(256);
    float* proj1 = (float*)alloc((size_t)N_NODES * 4 * 4);
    float* proj2 = (float*)alloc((size_t)N_NODES * 4 * 4);
    u16* Wqkv1t  = (u16*)alloc((size_t)1536 * 256 * 2);
    u16* Wqkv2t  = (u16*)alloc((size_t)1536 * 256 * 2);
    u16* Wproj1t = (u16*)alloc((size_t)256 * 512 * 2);
    u16* Wproj2t = (u16*)alloc((size_t)256 * 512 * 2);
    size_t off_common = off;

    // ---- big path: full T (2 sets x 20000x1536 bf16) + double cat
    u16* cat = (u16*)alloc(2ull * N_NODES * 512 * 2);
    u16* T1  = (u16*)alloc(2ull * N_NODES * 1536 * 2);
    u16* T2  = T1 + (size_t)N_NODES * 1536;
    bool big = (off <= ws_size);
    u16* Told = nullptr;
    if (!big) {
        off = off_common;
        cat  = (u16*)alloc((size_t)N_NODES * 512 * 2);
        Told = (u16*)alloc((size_t)N_NODES * 768 * 2);
        if (off > ws_size) {
            marker_kernel<<<1, 16, 0, stream>>>(out, 0x447A /*~1000*/);
            return;
        }
    }
    const int* dF = diag + 1;
    const int* dZ = diag + 2;

    const int NP1 = N_NODES + 1;
    hipMemsetAsync(cur, 0, 8ull * N_NODES * 4, stream);
    hipMemsetAsync(diag, 0, 256, stream);

    detect_kernel<<<1, 64, 0, stream>>>(feat1, diag);
    rpe_sums_kernel<<<1, 64, 0, stream>>>(Wrpe, brpe, rpe_s, dF);
    coordproj_kernel<<<(N_NODES * 4 + 255) / 256, 256, 0, stream>>>(coord1, dF, rpe_s, proj1, N_NODES);
    coordproj_kernel<<<(N_NODES * 4 + 255) / 256, 256, 0, stream>>>(coord2, dF, rpe_s, proj2, N_NODES);
    transpose_w_kernel<<<(1536 * 256 + 255) / 256, 256, 0, stream>>>(Wqkv1, dF, Wqkv1t, 256, 1536);
    transpose_w_kernel<<<(1536 * 256 + 255) / 256, 256, 0, stream>>>(Wqkv2, dF, Wqkv2t, 256, 1536);
    transpose_w_kernel<<<(256 * 512 + 255) / 256, 256, 0, stream>>>(Wproj1, dF, Wproj1t, 512, 256);
    transpose_w_kernel<<<(256 * 512 + 255) / 256, 256, 0, stream>>>(Wproj2, dF, Wproj2t, 512, 256);

    const int EB = 4 * N_EDGES / 256;
    count_kernel<<<EB, 256, 0, stream>>>(graph1, graph2, graph12, graph21, cur, rank);
    scan_kernel<<<4, 256, 0, stream>>>(cur, rowptr);
    fill_kernel<<<EB, 256, 0, stream>>>(graph1, graph2, graph12, graph21, rowptr, cur, rank, col);

    const dim3 blk(256);
    const int AG = (N_NODES + 3) / 4;

    if (big) {
        // QKV column map (from reference _qkv):
        //  T1: q11@0 k11@256 v11@512 | q12@768 k12@1024 v12@1280
        //  T2: q21@0 k21@256 v21@512 | q22@768 k22@1024 v22@1280
        u16* cat1 = cat;
        u16* cat2 = cat + (size_t)N_NODES * 512;
        // featb aliases cat: consumed by QKV GEMM before attn overwrites cat.
        u16* featb1 = cat;
        u16* featb2 = cat + (size_t)N_NODES * 256;
        const int NROW = (N_NODES + 127) / 128;   // 157

        tobf16_kernel<<<(2 * N_NODES * 256 / 8 + 255) / 256, blk, 0, stream>>>(
            feat1, feat2, dF, featb1, featb2);

        // QKV: M=20000, N=1536 (12 col-tiles), K=256
        gemm_pipe<<<dim3(2 * NROW * 12), blk, 0, stream>>>(
            featb1, featb2, 256, Wqkv1t, Wqkv2t, bqkv1, bqkv2, dF,
            T1, 0, (size_t)N_NODES * 1536, 1536, dZ, N_NODES, NROW, 12);

        // self 1: attn(k11, q11, v11, graph1, rpe1)
        attn3_kernel<<<AG, blk, 0, stream>>>(T1 + 0, T1 + 256, T1 + 512,
                                             rowptr + 0 * NP1, col + 0 * (size_t)N_EDGES,
                                             proj1, proj1, rpe_s + 12, 1, cat1 + 0, 1536);
        // cross 1<-2: attn(k21, q12, v21, graph21)
        attn3_kernel<<<AG, blk, 0, stream>>>(T1 + 768, T2 + 256, T2 + 512,
                                             rowptr + 3 * NP1, col + 3 * (size_t)N_EDGES,
                                             nullptr, nullptr, rpe_s + 12, 0, cat1 + 256, 1536);
        // self 2: attn(k22, q22, v22, graph2, rpe2)
        attn3_kernel<<<AG, blk, 0, stream>>>(T2 + 768, T2 + 1024, T2 + 1280,
                                             rowptr + 1 * NP1, col + 1 * (size_t)N_EDGES,
                                             proj2, proj2, rpe_s + 12, 1, cat2 + 0, 1536);
        // cross 2<-1: attn(k12, q21, v12, graph12)
        attn3_kernel<<<AG, blk, 0, stream>>>(T2 + 0, T1 + 1024, T1 + 1280,
                                             rowptr + 2 * NP1, col + 2 * (size_t)N_EDGES,
                                             nullptr, nullptr, rpe_s + 12, 0, cat2 + 256, 1536);

        // proj: M=20000, N=256 (2 col-tiles), K=512
        gemm_pipe<<<dim3(2 * NROW * 2), blk, 0, stream>>>(
            cat1, cat2, 512, Wproj1t, Wproj2t, bproj1, bproj2, dF,
            out, 0, (size_t)N_NODES * 256, 256, dF, N_NODES, NROW, 2);
        return;
    }

    // ------------------------------------------------------------ fallback (round-1 proven path)
    u16* T = Told;
    const int GY = (N_NODES + 127) / 128;
    gemm_mfma<<<dim3(6, GY), blk, 0, stream>>>(feat1, 256, dF, Wqkv1t + 0 * 256,
                                               bqkv1, 0, dF, T, 0, 768, dZ, N_NODES, 768, 256);
    attn3_kernel<<<AG, blk, 0, stream>>>(T, T + 256, T + 512, rowptr + 0 * NP1, col + 0 * (size_t)N_EDGES,
                                         proj1, proj1, rpe_s + 12, 1, cat + 0, 768);
    gemm_mfma<<<dim3(2, GY), blk, 0, stream>>>(feat1, 256, dF, Wqkv1t + (size_t)768 * 256,
                                               bqkv1, 768, dF, T, 0, 768, dZ, N_NODES, 256, 256);
    gemm_mfma<<<dim3(4, GY), blk, 0, stream>>>(feat2, 256, dF, Wqkv2t + (size_t)256 * 256,
                                               bqkv2, 256, dF, T, 256, 768, dZ, N_NODES, 512, 256);
    attn3_kernel<<<AG, blk, 0, stream>>>(T, T + 256, T + 512, rowptr + 3 * NP1, col + 3 * (size_t)N_EDGES,
                                         nullptr, nullptr, rpe_s + 12, 0, cat + 256, 768);
    gemm_mfma<<<dim3(2, GY), blk, 0, stream>>>(cat, 512, dZ, Wproj1t,
                                               bproj1, 0, dF, out, 0, 256, dF, N_NODES, 256, 512);

    gemm_mfma<<<dim3(6, GY), blk, 0, stream>>>(feat2, 256, dF, Wqkv2t + (size_t)768 * 256,
                                               bqkv2, 768, dF, T, 0, 768, dZ, N_NODES, 768, 256);
    attn3_kernel<<<AG, blk, 0, stream>>>(T, T + 256, T + 512, rowptr + 1 * NP1, col + 1 * (size_t)N_EDGES,
                                         proj2, proj2, rpe_s + 12, 1, cat + 0, 768);
    gemm_mfma<<<dim3(2, GY), blk, 0, stream>>>(feat2, 256, dF, Wqkv2t + 0,
                                               bqkv2, 0, dF, T, 0, 768, dZ, N_NODES, 256, 256);
    gemm_mfma<<<dim3(4, GY), blk, 0, stream>>>(feat1, 256, dF, Wqkv1t + (size_t)1024 * 256,
                                               bqkv1, 1024, dF, T, 256, 768, dZ, N_NODES, 512, 256);
    attn3_kernel<<<AG, blk, 0, stream>>>(T, T + 256, T + 512, rowptr + 2 * NP1, col + 2 * (size_t)N_EDGES,
                                         nullptr, nullptr, rpe_s + 12, 0, cat + 256, 768);
    gemm_mfma<<<dim3(2, GY), blk, 0, stream>>>(cat, 512, dZ, Wproj2t,
                                               bproj2, 0, dF, out, (size_t)N_NODES * 256, 256, dF,
                                               N_NODES, 256, 512);
}

// Round 14
// 505.630 us; speedup vs baseline: 1.0993x; 1.0993x over previous
//
#include <hip/hip_runtime.h>
#include <stdint.h>
#include <stddef.h>

#define N_NODES 20000
#define N_EDGES 320000
#define NCH 79   // ceil(N_NODES/256)

typedef unsigned short u16;
typedef __attribute__((ext_vector_type(8))) short bf16x8;
typedef __attribute__((ext_vector_type(8))) unsigned short u16x8;
typedef __attribute__((ext_vector_type(4))) float f32x4;

__device__ __forceinline__ float bf2f(u16 u) {
    union { unsigned int i; float f; } v; v.i = ((unsigned int)u) << 16; return v.f;
}
__device__ __forceinline__ u16 f2bf(float f) {
    union { float f; unsigned int i; } v; v.f = f;
    unsigned int x = v.i;
    unsigned int r = x + 0x7fffu + ((x >> 16) & 1u);
    return (u16)(r >> 16);
}
__device__ __forceinline__ int clampi(int v, int lo, int hi) {
    return v < lo ? lo : (v > hi ? hi : v);
}
__device__ __forceinline__ float ld1(const void* p, size_t i, int f32) {
    return f32 ? ((const float*)p)[i] : bf2f(((const u16*)p)[i]);
}

// async 16B global -> LDS (wave-uniform LDS base + lane*16; global addr per-lane)
__device__ __forceinline__ void async_ld16(void* lds, const void* g) {
    __builtin_amdgcn_global_load_lds(
        (const __attribute__((address_space(1))) unsigned int*)g,
        (__attribute__((address_space(3))) unsigned int*)lds,
        16, 0, 0);
}

// bijective chunked XCD transform: hw id -> logical id; each XCD gets a
// contiguous chunk of logical ids. VERIFIED (r7 bisect): passes, FETCH 84->23MB.
__device__ __forceinline__ int xcd_chunk(int b, int nwg) {
    int x = b & 7, idx = b >> 3;
    int q = nwg >> 3, r = nwg & 7;
    return ((x < r) ? (x * (q + 1)) : (r * (q + 1) + (x - r) * q)) + idx;
}

__global__ void marker_kernel(u16* out, u16 code) { out[threadIdx.x] = code; }

// dtype sniff + sentinel. diag[0]=sentinel, diag[1]=fp32 flag, diag[2]=const 0
__global__ void detect_kernel(const void* feat, int* diag) {
    int lane = threadIdx.x;
    int weird = 0;
    const u16* p = (const u16*)feat;
    for (int i = lane; i < 512; i += 64) {
        float v = bf2f(p[i]);
        float a = fabsf(v);
        if (!(a <= 1e4f) || (a != 0.f && a < 1e-6f)) weird++;
    }
#pragma unroll
    for (int off = 32; off > 0; off >>= 1) weird += __shfl_xor(weird, off, 64);
    if (lane == 0) { diag[0] = 123456; diag[1] = (weird > 51) ? 1 : 0; diag[2] = 0; }
}

// rpe collapse: out[p*4+h] = sum_d Wrpe[p][h*64+d]; out[12+h] = sum_d brpe[h*64+d]
__global__ void rpe_sums_kernel(const void* __restrict__ Wrpe, const void* __restrict__ brpe,
                                float* __restrict__ out, const int* __restrict__ dflag) {
    int f32 = dflag[0];
    int t = threadIdx.x;
    if (t < 12) {
        int p = t >> 2, h = t & 3;
        float s = 0.f;
        for (int d = 0; d < 64; ++d) s += ld1(Wrpe, p * 256 + h * 64 + d, f32);
        out[t] = s;
    } else if (t < 16) {
        int h = t - 12;
        float s = 0.f;
        for (int d = 0; d < 64; ++d) s += ld1(brpe, h * 64 + d, f32);
        out[12 + h] = s;
    }
}

// proj[n*4+h] = sum_p coord[n,p] * rpe_sums[p*4+h]
__global__ __launch_bounds__(256) void coordproj_kernel(const void* __restrict__ coord,
                                                        const int* __restrict__ dflag,
                                                        const float* __restrict__ rs,
                                                        float* __restrict__ proj, int n) {
    int i = blockIdx.x * 256 + threadIdx.x;
    if (i >= n * 4) return;
    int f32 = dflag[0];
    int node = i >> 2, h = i & 3;
    float s = ld1(coord, (size_t)node * 3 + 0, f32) * rs[0 * 4 + h]
            + ld1(coord, (size_t)node * 3 + 1, f32) * rs[1 * 4 + h]
            + ld1(coord, (size_t)node * 3 + 2, f32) * rs[2 * 4 + h];
    proj[i] = s;
}

// Wt[n*K + k] = bf16(W[k*N + n])  (weight transpose + convert)
__global__ __launch_bounds__(256) void transpose_w_kernel(const void* __restrict__ W,
                                                          const int* __restrict__ dflag,
                                                          u16* __restrict__ Wt, int K, int N) {
    int f32 = dflag[0];
    int i = blockIdx.x * 256 + threadIdx.x;
    if (i >= K * N) return;
    int n = i / K, k = i - n * K;
    Wt[i] = f2bf(ld1(W, (size_t)k * N + n, f32));
}

// feat (f32 or bf16) -> bf16, both sets, vectorized 8/thread
__global__ __launch_bounds__(256) void tobf16_kernel(
        const void* __restrict__ a, const void* __restrict__ b,
        const int* __restrict__ dflag, u16* __restrict__ oa, u16* __restrict__ ob) {
    const int PER = N_NODES * 256 / 8;   // 640000
    int idx = blockIdx.x * 256 + threadIdx.x;
    if (idx >= 2 * PER) return;
    int set = idx >= PER;
    int j = (idx - set * PER) * 8;
    const void* src = set ? b : a;
    u16* dst = set ? ob : oa;
    int f32 = dflag[0];
    u16x8 o;
    if (f32) {
        const float* p = (const float*)src + j;
        float4 u0 = *(const float4*)p, u1 = *(const float4*)(p + 4);
        o[0] = f2bf(u0.x); o[1] = f2bf(u0.y); o[2] = f2bf(u0.z); o[3] = f2bf(u0.w);
        o[4] = f2bf(u1.x); o[5] = f2bf(u1.y); o[6] = f2bf(u1.z); o[7] = f2bf(u1.w);
    } else {
        o = *(const u16x8*)((const u16*)src + j);
    }
    *(u16x8*)(dst + j) = o;
}

// ---------------------------------------------------------------- CSR build
// r12: split-copy atomics (copy = gi*2 + h, h=(b>>2)&1) -> deg lines touched
// by one XCD residue class only. rank stores (h<<15)|pos.
__global__ __launch_bounds__(256) void count_kernel(
        const int* __restrict__ g0, const int* __restrict__ g1,
        const int* __restrict__ g2, const int* __restrict__ g3,
        int* __restrict__ deg, u16* __restrict__ rank) {
    int b = blockIdx.x;
    int gi = b & 3;
    int h = (b >> 2) & 1;
    int e = (b >> 2) * 256 + (int)threadIdx.x;
    if (e >= N_EDGES) return;
    const int* g = (gi == 0) ? g0 : (gi == 1) ? g1 : (gi == 2) ? g2 : g3;
    int dst = clampi(g[e], 0, N_NODES - 1);
    int pos = atomicAdd(&deg[(gi * 2 + h) * N_NODES + dst], 1);
    pos = pos & 0x7fff;
    rank[(size_t)gi * N_EDGES + e] = (u16)((h << 15) | pos);
}

// r13 hierarchical scan (infra-failed last round, resubmitted unchanged):
// coalesced 3-phase replacing the grid-4 serial-chunk scan (60us latency-bound).
// scan1: per-chunk LDS scan; tmp[i] = exclusive within chunk; csum[ch] = total.
__global__ __launch_bounds__(256) void scan1_kernel(const int* __restrict__ cur,
                                                    int* __restrict__ tmp,
                                                    int* __restrict__ csum) {
    int b = blockIdx.x;
    int g = b / NCH, ch = b - g * NCH;
    int tid = threadIdx.x;
    int i = ch * 256 + tid;
    const int* d0 = cur + (g * 2 + 0) * N_NODES;
    const int* d1 = cur + (g * 2 + 1) * N_NODES;
    int val = (i < N_NODES) ? (d0[i] + d1[i]) : 0;
    __shared__ int buf[256];
    buf[tid] = val;
    __syncthreads();
    for (int off = 1; off < 256; off <<= 1) {
        int x = (tid >= off) ? buf[tid - off] : 0;
        __syncthreads();
        buf[tid] += x;
        __syncthreads();
    }
    if (i < N_NODES) tmp[g * N_NODES + i] = buf[tid] - val;
    if (tid == 255) csum[g * NCH + ch] = buf[255];
}

// scan2: scan the NCH chunk totals per graph; coff = exclusive; rowptr[N]=total.
__global__ __launch_bounds__(256) void scan2_kernel(const int* __restrict__ csum,
                                                    int* __restrict__ coff,
                                                    int* __restrict__ rowptr) {
    int g = blockIdx.x;
    int tid = threadIdx.x;
    int v = (tid < NCH) ? csum[g * NCH + tid] : 0;
    __shared__ int buf[256];
    buf[tid] = v;
    __syncthreads();
    for (int off = 1; off < 256; off <<= 1) {
        int x = (tid >= off) ? buf[tid - off] : 0;
        __syncthreads();
        buf[tid] += x;
        __syncthreads();
    }
    if (tid < NCH) coff[g * NCH + tid] = buf[tid] - v;
    if (tid == 255) rowptr[g * (N_NODES + 1) + N_NODES] = buf[255];
}

// scan3: rowptr[i] = tmp[i] + coff[chunk], fully coalesced.
__global__ __launch_bounds__(256) void scan3_kernel(const int* __restrict__ tmp,
                                                    const int* __restrict__ coff,
                                                    int* __restrict__ rowptr) {
    int b = blockIdx.x;
    int g = b / NCH, ch = b - g * NCH;
    int i = ch * 256 + (int)threadIdx.x;
    if (i < N_NODES)
        rowptr[g * (N_NODES + 1) + i] = tmp[g * N_NODES + i] + coff[g * NCH + ch];
}

// fill: NO atomics — pos = rowptr[dst] + (h ? deg0[dst] : 0) + rank. u16 col.
__global__ __launch_bounds__(256) void fill_kernel(
        const int* __restrict__ g0, const int* __restrict__ g1,
        const int* __restrict__ g2, const int* __restrict__ g3,
        const int* __restrict__ rowptr, const int* __restrict__ cur,
        const u16* __restrict__ rank, u16* __restrict__ col) {
    int b = blockIdx.x;
    int gi = b & 3;
    int e = (b >> 2) * 256 + (int)threadIdx.x;
    if (e >= N_EDGES) return;
    const int* g = (gi == 0) ? g0 : (gi == 1) ? g1 : (gi == 2) ? g2 : g3;
    int dst = clampi(g[e], 0, N_NODES - 1);
    int src = clampi(g[N_EDGES + e], 0, N_NODES - 1);
    u16 rk = rank[(size_t)gi * N_EDGES + e];
    int h = rk >> 15, r = rk & 0x7fff;
    int base = h ? cur[(gi * 2 + 0) * N_NODES + dst] : 0;
    int pos = rowptr[gi * (N_NODES + 1) + dst] + base + r;
    if (pos >= 0 && pos < N_EDGES)
        col[(size_t)gi * N_EDGES + pos] = (u16)src;
}

// ---------------------------------------------------------------- classic MFMA GEMM (fallback path)
__global__ __launch_bounds__(256) void gemm_mfma(
        const void* __restrict__ A, int lda, const int* __restrict__ aflag,
        const u16* __restrict__ Bt,
        const void* __restrict__ bias, size_t biasoff, const int* __restrict__ bflag,
        void* __restrict__ C, size_t coff, int ldc, const int* __restrict__ cflag,
        int M, int N, int K) {
    __shared__ __align__(16) u16 As[128 * 40];
    __shared__ __align__(16) u16 Bs[128 * 40];
    const int f32a = aflag[0], f32b = bflag[0], f32c = cflag[0];
    const int t = threadIdx.x;
    const int lane = t & 63, wv = t >> 6;
    const int wm = (wv >> 1) * 64, wn = (wv & 1) * 64;
    const int m0 = blockIdx.y * 128, n0 = blockIdx.x * 128;
    const int l15 = lane & 15, lq = lane >> 4;

    f32x4 acc[4][4];
#pragma unroll
    for (int i = 0; i < 4; ++i)
#pragma unroll
        for (int j = 0; j < 4; ++j) acc[i][j] = (f32x4){0.f, 0.f, 0.f, 0.f};

    const int sr = t >> 1, skc = (t & 1) * 16;

    for (int k0 = 0; k0 < K; k0 += 32) {
        __syncthreads();
        {
            __align__(16) u16 tmp[16];
            int gm = m0 + sr;
            if (gm < M) {
                if (f32a) {
                    const float* ap = (const float*)A + (size_t)gm * lda + k0 + skc;
#pragma unroll
                    for (int i = 0; i < 16; i += 4) {
                        float4 u = *(const float4*)(ap + i);
                        tmp[i] = f2bf(u.x); tmp[i + 1] = f2bf(u.y);
                        tmp[i + 2] = f2bf(u.z); tmp[i + 3] = f2bf(u.w);
                    }
                } else {
                    const u16* ap = (const u16*)A + (size_t)gm * lda + k0 + skc;
                    *(u16x8*)&tmp[0] = *(const u16x8*)ap;
                    *(u16x8*)&tmp[8] = *(const u16x8*)(ap + 8);
                }
            } else {
#pragma unroll
                for (int i = 0; i < 16; ++i) tmp[i] = 0;
            }
            *(u16x8*)&As[sr * 40 + skc] = *(u16x8*)&tmp[0];
            *(u16x8*)&As[sr * 40 + skc + 8] = *(u16x8*)&tmp[8];
        }
        {
            const u16* bp = Bt + (size_t)(n0 + sr) * K + k0 + skc;
            u16x8 b0 = *(const u16x8*)bp;
            u16x8 b1 = *(const u16x8*)(bp + 8);
            *(u16x8*)&Bs[sr * 40 + skc] = b0;
            *(u16x8*)&Bs[sr * 40 + skc + 8] = b1;
        }
        __syncthreads();
        bf16x8 af[4], bfr[4];
#pragma unroll
        for (int mt = 0; mt < 4; ++mt)
            af[mt] = *(const bf16x8*)&As[(wm + mt * 16 + l15) * 40 + lq * 8];
#pragma unroll
        for (int nt = 0; nt < 4; ++nt)
            bfr[nt] = *(const bf16x8*)&Bs[(wn + nt * 16 + l15) * 40 + lq * 8];
#pragma unroll
        for (int mt = 0; mt < 4; ++mt)
#pragma unroll
            for (int nt = 0; nt < 4; ++nt)
                acc[mt][nt] = __builtin_amdgcn_mfma_f32_16x16x32_bf16(af[mt], bfr[nt], acc[mt][nt], 0, 0, 0);
    }
#pragma unroll
    for (int mt = 0; mt < 4; ++mt) {
#pragma unroll
        for (int nt = 0; nt < 4; ++nt) {
            int gn = n0 + wn + nt * 16 + l15;
            float bb = ld1(bias, biasoff + gn, f32b);
#pragma unroll
            for (int r = 0; r < 4; ++r) {
                int gm = m0 + wm + mt * 16 + lq * 4 + r;
                if (gm < M) {
                    float v = acc[mt][nt][r] + bb;
                    size_t ic = coff + (size_t)gm * ldc + gn;
                    if (f32c) ((float*)C)[ic] = v;
                    else      ((u16*)C)[ic] = f2bf(v);
                }
            }
        }
    }
}

// ---------------------------------------------------------------- pipelined dual GEMM (m97 structure)
// r11-verified: BK=64, pre-swizzled global source + swizzled read (linear LDS
// dest for global_load_lds), 32KB LDS + (256,4) -> 4 blocks/CU. XCD map
// r7-verified; swizzled LDS C-stage epilogue r10-verified.
__global__ __launch_bounds__(256, 4) void gemm_pipe(
        const u16* __restrict__ A1, const u16* __restrict__ A2, int K,
        const u16* __restrict__ Bt1, const u16* __restrict__ Bt2,
        const void* __restrict__ bias1, const void* __restrict__ bias2,
        const int* __restrict__ bflag,
        void* __restrict__ C, size_t coff1, size_t coff2, int ldc,
        const int* __restrict__ cflag,
        int M, int nr, int nc) {
    __shared__ __align__(16) u16 S[16384];   // As(16KB) | Bs(16KB), reused as C-stage
    u16* As = S;
    u16* Bs = S + 8192;
    const int f32b = bflag[0], f32c = cflag[0];
    const int t = threadIdx.x;
    const int half = nr * nc;
    const int nwg = 2 * half;
    int b = xcd_chunk(blockIdx.x, nwg);
    const int set = (b >= half) ? 1 : 0;
    b -= set * half;
    const int c = b % nc, r = b / nc;
    const int m0 = r * 128, n0 = c * 128;
    const u16* A   = set ? A2 : A1;
    const u16* Bt  = set ? Bt2 : Bt1;
    const void* bias = set ? bias2 : bias1;
    const size_t coff = set ? coff2 : coff1;

    const int lane = t & 63, wv = t >> 6;
    const int wm = (wv >> 1) * 64, wn = (wv & 1) * 64;
    const int l15 = lane & 15, lq = lane >> 4;

    // staging: wave wv stages LDS rows [wv*32, wv*32+32) x 64 cols in 4+4 instrs.
    const int srow8 = lane >> 3;             // 0..7 (== row&7 of staged row)
    const int sgsw  = ((lane & 7) ^ srow8) * 8;  // swizzled source granule, u16 units
    const u16* agp[4];
    const u16* bgp[4];
    u16 *lap[4], *lbp[4];
#pragma unroll
    for (int i = 0; i < 4; ++i) {
        int ra = m0 + wv * 32 + i * 8 + srow8; if (ra > M - 1) ra = M - 1;
        int rb = n0 + wv * 32 + i * 8 + srow8;
        agp[i] = A  + (size_t)ra * K + sgsw;
        bgp[i] = Bt + (size_t)rb * K + sgsw;
        lap[i] = &As[(wv * 32 + i * 8) * 64];
        lbp[i] = &Bs[(wv * 32 + i * 8) * 64];
    }
    const int l7 = l15 & 7;                  // row&7 of fragment rows

    f32x4 acc[4][4];
#pragma unroll
    for (int i = 0; i < 4; ++i)
#pragma unroll
        for (int j = 0; j < 4; ++j) acc[i][j] = (f32x4){0.f, 0.f, 0.f, 0.f};

    for (int k0 = 0; k0 < K; k0 += 64) {
        __syncthreads();                       // protect prev iteration's readers
#pragma unroll
        for (int i = 0; i < 4; ++i) async_ld16(lap[i], agp[i] + k0);
#pragma unroll
        for (int i = 0; i < 4; ++i) async_ld16(lbp[i], bgp[i] + k0);
        __syncthreads();                       // vmcnt(0) drain -> LDS valid
#pragma unroll
        for (int h2 = 0; h2 < 2; ++h2) {
            const int gq = lq + h2 * 4;        // wanted granule 0..7
            bf16x8 af[4], bfr[4];
#pragma unroll
            for (int mt = 0; mt < 4; ++mt)
                af[mt] = *(const bf16x8*)&As[(wm + mt * 16 + l15) * 64 + ((gq ^ l7) << 3)];
#pragma unroll
            for (int nt = 0; nt < 4; ++nt)
                bfr[nt] = *(const bf16x8*)&Bs[(wn + nt * 16 + l15) * 64 + ((gq ^ l7) << 3)];
#pragma unroll
            for (int mt = 0; mt < 4; ++mt)
#pragma unroll
                for (int nt = 0; nt < 4; ++nt)
                    acc[mt][nt] = __builtin_amdgcn_mfma_f32_16x16x32_bf16(
                        bfr[nt], af[mt], acc[mt][nt], 0, 0, 0);
        }
    }

    // ---- epilogue via LDS stage -> full-line stores (r10-verified, swizzled)
    if (!f32c) {
        u16* Cs = S;                           // 64 rows x 128 cols bf16 = 16 KB
#pragma unroll
        for (int p = 0; p < 2; ++p) {
            __syncthreads();
            if ((wv >> 1) == p) {
#pragma unroll
                for (int nt = 0; nt < 4; ++nt) {
                    int lc = wn + nt * 16 + lq * 4;
                    int gn0 = n0 + lc;
                    float b0 = ld1(bias, gn0 + 0, f32b);
                    float b1 = ld1(bias, gn0 + 1, f32b);
                    float b2 = ld1(bias, gn0 + 2, f32b);
                    float b3 = ld1(bias, gn0 + 3, f32b);
#pragma unroll
                    for (int mt = 0; mt < 4; ++mt) {
                        ushort4 o;
                        o.x = f2bf(acc[mt][nt][0] + b0);
                        o.y = f2bf(acc[mt][nt][1] + b1);
                        o.z = f2bf(acc[mt][nt][2] + b2);
                        o.w = f2bf(acc[mt][nt][3] + b3);
                        // swizzled deposit: row&15 == l15 for writers
                        *(ushort4*)&Cs[(mt * 16 + l15) * 128 + (lc ^ (l15 << 3))] = o;
                    }
                }
            }
            __syncthreads();
#pragma unroll
            for (int it = 0; it < 4; ++it) {   // 64 rows x 16 chunks of 16B
                int idx = it * 256 + t;
                int row = idx >> 4, ch = idx & 15;
                int gm = m0 + p * 64 + row;
                if (gm < M)
                    *(u16x8*)((u16*)C + coff + (size_t)gm * ldc + n0 + ch * 8) =
                        *(const u16x8*)&Cs[row * 128 + ((ch * 8) ^ ((row & 15) << 3))];
            }
        }
    } else {
        float* Cs = (float*)S;                 // 32 rows x 128 cols f32 = 16 KB
#pragma unroll
        for (int p = 0; p < 4; ++p) {
            __syncthreads();
            if ((wv >> 1) == (p >> 1)) {
                int mtb = (p & 1) * 2;
#pragma unroll
                for (int nt = 0; nt < 4; ++nt) {
                    int lc = wn + nt * 16 + lq * 4;
                    int gn0 = n0 + lc;
                    float b0 = ld1(bias, gn0 + 0, f32b);
                    float b1 = ld1(bias, gn0 + 1, f32b);
                    float b2 = ld1(bias, gn0 + 2, f32b);
                    float b3 = ld1(bias, gn0 + 3, f32b);
#pragma unroll
                    for (int mi = 0; mi < 2; ++mi) {
                        int mt = mtb + mi;
                        f32x4 o;
                        o[0] = acc[mt][nt][0] + b0;
                        o[1] = acc[mt][nt][1] + b1;
                        o[2] = acc[mt][nt][2] + b2;
                        o[3] = acc[mt][nt][3] + b3;
                        *(f32x4*)&Cs[(mi * 16 + l15) * 128 + lc] = o;
                    }
                }
            }
            __syncthreads();
#pragma unroll
            for (int it = 0; it < 4; ++it) {   // 32 rows x 32 chunks of 16B
                int idx = it * 256 + t;
                int row = idx >> 5, ch = idx & 31;
                int gm = m0 + p * 32 + row;
                if (gm < M)
                    *(float4*)((float*)C + coff + (size_t)gm * ldc + n0 + ch * 4) =
                        *(const float4*)&Cs[row * 128 + ch * 4];
            }
        }
    }
}

// ---------------------------------------------------------------- edge attention v3
// wave per dst node; lane = h*16+j; lane owns d = j*4..j*4+3 of head h. ldt = row stride.
__global__ __launch_bounds__(256) void attn3_kernel(
        const u16* __restrict__ Q, const u16* __restrict__ Kp, const u16* __restrict__ Vp,
        const int* __restrict__ rowptr, const u16* __restrict__ col,
        const float* __restrict__ projN, const float* __restrict__ projS,
        const float* __restrict__ rb, int use_rpe,
        u16* __restrict__ outp, int ldt) {
    int lane = threadIdx.x & 63;
    int node = blockIdx.x * 4 + (threadIdx.x >> 6);
    if (node >= N_NODES) return;
    int h = lane >> 4;
    int off = h * 64 + (lane & 15) * 4;

    ushort4 qu = *(const ushort4*)(Q + (size_t)node * ldt + off);
    float q0 = bf2f(qu.x), q1 = bf2f(qu.y), q2 = bf2f(qu.z), q3 = bf2f(qu.w);
    float base = use_rpe ? (projN[node * 4 + h] + rb[h]) : 0.f;

    float m = -1e30f, l = 0.f, a0 = 0.f, a1 = 0.f, a2 = 0.f, a3 = 0.f;
    int e0 = rowptr[node], e1 = rowptr[node + 1];
    e0 = clampi(e0, 0, N_EDGES);
    e1 = clampi(e1, e0, N_EDGES);
    int e = e0;
    for (; e + 4 <= e1; e += 4) {
        int s0 = clampi((int)col[e + 0], 0, N_NODES - 1);
        int s1 = clampi((int)col[e + 1], 0, N_NODES - 1);
        int s2 = clampi((int)col[e + 2], 0, N_NODES - 1);
        int s3 = clampi((int)col[e + 3], 0, N_NODES - 1);
        ushort4 k0 = *(const ushort4*)(Kp + (size_t)s0 * ldt + off);
        ushort4 k1 = *(const ushort4*)(Kp + (size_t)s1 * ldt + off);
        ushort4 k2 = *(const ushort4*)(Kp + (size_t)s2 * ldt + off);
        ushort4 k3 = *(const ushort4*)(Kp + (size_t)s3 * ldt + off);
        ushort4 v0 = *(const ushort4*)(Vp + (size_t)s0 * ldt + off);
        ushort4 v1 = *(const ushort4*)(Vp + (size_t)s1 * ldt + off);
        ushort4 v2 = *(const ushort4*)(Vp + (size_t)s2 * ldt + off);
        ushort4 v3 = *(const ushort4*)(Vp + (size_t)s3 * ldt + off);
        float t0 = q0 * bf2f(k0.x) + q1 * bf2f(k0.y) + q2 * bf2f(k0.z) + q3 * bf2f(k0.w);
        float t1 = q0 * bf2f(k1.x) + q1 * bf2f(k1.y) + q2 * bf2f(k1.z) + q3 * bf2f(k1.w);
        float t2 = q0 * bf2f(k2.x) + q1 * bf2f(k2.y) + q2 * bf2f(k2.z) + q3 * bf2f(k2.w);
        float t3 = q0 * bf2f(k3.x) + q1 * bf2f(k3.y) + q2 * bf2f(k3.z) + q3 * bf2f(k3.w);
#pragma unroll
        for (int sh = 1; sh <= 8; sh <<= 1) {
            t0 += __shfl_xor(t0, sh, 64);
            t1 += __shfl_xor(t1, sh, 64);
            t2 += __shfl_xor(t2, sh, 64);
            t3 += __shfl_xor(t3, sh, 64);
        }
        if (use_rpe) {
            t0 += base - projS[s0 * 4 + h];
            t1 += base - projS[s1 * 4 + h];
            t2 += base - projS[s2 * 4 + h];
            t3 += base - projS[s3 * 4 + h];
        }
        float mx = fmaxf(fmaxf(fmaxf(t0, t1), fmaxf(t2, t3)), m);
        float sc = __expf(m - mx);
        float p0 = __expf(t0 - mx), p1 = __expf(t1 - mx);
        float p2 = __expf(t2 - mx), p3 = __expf(t3 - mx);
        l = l * sc + (p0 + p1 + p2 + p3);
        a0 = a0 * sc + p0 * bf2f(v0.x) + p1 * bf2f(v1.x) + p2 * bf2f(v2.x) + p3 * bf2f(v3.x);
        a1 = a1 * sc + p0 * bf2f(v0.y) + p1 * bf2f(v1.y) + p2 * bf2f(v2.y) + p3 * bf2f(v3.y);
        a2 = a2 * sc + p0 * bf2f(v0.z) + p1 * bf2f(v1.z) + p2 * bf2f(v2.z) + p3 * bf2f(v3.z);
        a3 = a3 * sc + p0 * bf2f(v0.w) + p1 * bf2f(v1.w) + p2 * bf2f(v2.w) + p3 * bf2f(v3.w);
        m = mx;
    }
    for (; e < e1; ++e) {
        int src = clampi((int)col[e], 0, N_NODES - 1);
        ushort4 ku = *(const ushort4*)(Kp + (size_t)src * ldt + off);
        ushort4 vu = *(const ushort4*)(Vp + (size_t)src * ldt + off);
        float tv = q0 * bf2f(ku.x) + q1 * bf2f(ku.y) + q2 * bf2f(ku.z) + q3 * bf2f(ku.w);
        tv += __shfl_xor(tv, 1, 64);
        tv += __shfl_xor(tv, 2, 64);
        tv += __shfl_xor(tv, 4, 64);
        tv += __shfl_xor(tv, 8, 64);
        if (use_rpe) tv += base - projS[src * 4 + h];
        float mn = fmaxf(m, tv);
        float sc = __expf(m - mn), p = __expf(tv - mn);
        l = l * sc + p;
        a0 = a0 * sc + p * bf2f(vu.x);
        a1 = a1 * sc + p * bf2f(vu.y);
        a2 = a2 * sc + p * bf2f(vu.z);
        a3 = a3 * sc + p * bf2f(vu.w);
        m = mn;
    }
    float inv = l > 0.f ? 1.f / l : 0.f;
    ushort4 o;
    o.x = f2bf(a0 * inv); o.y = f2bf(a1 * inv); o.z = f2bf(a2 * inv); o.w = f2bf(a3 * inv);
    *(ushort4*)(outp + (size_t)node * 512 + off) = o;
}

// ---------------------------------------------------------------- launch
extern "C" void kernel_launch(void* const* d_in, const int* in_sizes, int n_in,
                              void* d_out, int out_size, void* d_ws, size_t ws_size,
                              hipStream_t stream) {
    const void* feat1  = d_in[0];
    const void* coord1 = d_in[1];
    const void* feat2  = d_in[2];
    const void* coord2 = d_in[3];
    const void* Wqkv1  = d_in[4];
    const void* bqkv1  = d_in[5];
    const void* Wqkv2  = d_in[6];
    const void* bqkv2  = d_in[7];
    const void* Wproj1 = d_in[8];
    const void* bproj1 = d_in[9];
    const void* Wproj2 = d_in[10];
    const void* bproj2 = d_in[11];
    const void* Wrpe   = d_in[12];
    const void* brpe   = d_in[13];
    const int* graph1  = (const int*)d_in[14];
    const int* graph2  = (const int*)d_in[15];
    const int* graph12 = (const int*)d_in[16];
    const int* graph21 = (const int*)d_in[17];
    u16* out = (u16*)d_out;

    {   // layout assertion
        static const int expect[18] = {
            N_NODES * 256, N_NODES * 3, N_NODES * 256, N_NODES * 3,
            256 * 1536, 1536, 256 * 1536, 1536,
            512 * 256, 256, 512 * 256, 256,
            3 * 256, 256,
            2 * N_EDGES, 2 * N_EDGES, 2 * N_EDGES, 2 * N_EDGES };
        bool ok = (n_in == 18) && (out_size == 2 * N_NODES * 256);
        if (ok) for (int i = 0; i < 18; ++i) if (in_sizes[i] != expect[i]) ok = false;
        if (!ok) { marker_kernel<<<1, 16, 0, stream>>>(out, 0x4496 /*~1200*/); return; }
    }

    char* w = (char*)d_ws;
    size_t off = 0;
    auto alloc = [&](size_t bytes) { void* p = w + off; off += (bytes + 255) & ~(size_t)255; return p; };
    int* rowptr  = (int*)alloc(4ull * (N_NODES + 1) * 4);
    int* cur     = (int*)alloc(8ull * N_NODES * 4);   // r12: 2 copies per graph
    u16* col     = (u16*)alloc(4ull * N_EDGES * 2);
    u16* rank    = (u16*)alloc(4ull * N_EDGES * 2);
    int* tmpscan = (int*)alloc(4ull * N_NODES * 4);   // r13: per-element excl prefix
    int* csum    = (int*)alloc(4ull * NCH * 4);
    int* coffb   = (int*)alloc(4ull * NCH * 4);
    float* rpe_s = (float*)alloc(64);
    int* diag    = (int*)alloc(256);
    float* proj1 = (float*)alloc((size_t)N_NODES * 4 * 4);
    float* proj2 = (float*)alloc((size_t)N_NODES * 4 * 4);
    u16* Wqkv1t  = (u16*)alloc((size_t)1536 * 256 * 2);
    u16* Wqkv2t  = (u16*)alloc((size_t)1536 * 256 * 2);
    u16* Wproj1t = (u16*)alloc((size_t)256 * 512 * 2);
    u16* Wproj2t = (u16*)alloc((size_t)256 * 512 * 2);
    size_t off_common = off;

    // ---- big path: full T (2 sets x 20000x1536 bf16) + double cat
    u16* cat = (u16*)alloc(2ull * N_NODES * 512 * 2);
    u16* T1  = (u16*)alloc(2ull * N_NODES * 1536 * 2);
    u16* T2  = T1 + (size_t)N_NODES * 1536;
    bool big = (off <= ws_size);
    u16* Told = nullptr;
    if (!big) {
        off = off_common;
        cat  = (u16*)alloc((size_t)N_NODES * 512 * 2);
        Told = (u16*)alloc((size_t)N_NODES * 768 * 2);
        if (off > ws_size) {
            marker_kernel<<<1, 16, 0, stream>>>(out, 0x447A /*~1000*/);
            return;
        }
    }
    const int* dF = diag + 1;
    const int* dZ = diag + 2;

    const int NP1 = N_NODES + 1;
    hipMemsetAsync(cur, 0, 8ull * N_NODES * 4, stream);
    hipMemsetAsync(diag, 0, 256, stream);

    detect_kernel<<<1, 64, 0, stream>>>(feat1, diag);
    rpe_sums_kernel<<<1, 64, 0, stream>>>(Wrpe, brpe, rpe_s, dF);
    coordproj_kernel<<<(N_NODES * 4 + 255) / 256, 256, 0, stream>>>(coord1, dF, rpe_s, proj1, N_NODES);
    coordproj_kernel<<<(N_NODES * 4 + 255) / 256, 256, 0, stream>>>(coord2, dF, rpe_s, proj2, N_NODES);
    transpose_w_kernel<<<(1536 * 256 + 255) / 256, 256, 0, stream>>>(Wqkv1, dF, Wqkv1t, 256, 1536);
    transpose_w_kernel<<<(1536 * 256 + 255) / 256, 256, 0, stream>>>(Wqkv2, dF, Wqkv2t, 256, 1536);
    transpose_w_kernel<<<(256 * 512 + 255) / 256, 256, 0, stream>>>(Wproj1, dF, Wproj1t, 512, 256);
    transpose_w_kernel<<<(256 * 512 + 255) / 256, 256, 0, stream>>>(Wproj2, dF, Wproj2t, 512, 256);

    const int EB = 4 * N_EDGES / 256;
    count_kernel<<<EB, 256, 0, stream>>>(graph1, graph2, graph12, graph21, cur, rank);
    scan1_kernel<<<4 * NCH, 256, 0, stream>>>(cur, tmpscan, csum);
    scan2_kernel<<<4, 256, 0, stream>>>(csum, coffb, rowptr);
    scan3_kernel<<<4 * NCH, 256, 0, stream>>>(tmpscan, coffb, rowptr);
    fill_kernel<<<EB, 256, 0, stream>>>(graph1, graph2, graph12, graph21, rowptr, cur, rank, col);

    const dim3 blk(256);
    const int AG = (N_NODES + 3) / 4;

    if (big) {
        // QKV column map (from reference _qkv):
        //  T1: q11@0 k11@256 v11@512 | q12@768 k12@1024 v12@1280
        //  T2: q21@0 k21@256 v21@512 | q22@768 k22@1024 v22@1280
        u16* cat1 = cat;
        u16* cat2 = cat + (size_t)N_NODES * 512;
        // featb aliases cat: consumed by QKV GEMM before attn overwrites cat.
        u16* featb1 = cat;
        u16* featb2 = cat + (size_t)N_NODES * 256;
        const int NROW = (N_NODES + 127) / 128;   // 157

        tobf16_kernel<<<(2 * N_NODES * 256 / 8 + 255) / 256, blk, 0, stream>>>(
            feat1, feat2, dF, featb1, featb2);

        // QKV: M=20000, N=1536 (12 col-tiles), K=256
        gemm_pipe<<<dim3(2 * NROW * 12), blk, 0, stream>>>(
            featb1, featb2, 256, Wqkv1t, Wqkv2t, bqkv1, bqkv2, dF,
            T1, 0, (size_t)N_NODES * 1536, 1536, dZ, N_NODES, NROW, 12);

        // self 1: attn(k11, q11, v11, graph1, rpe1)
        attn3_kernel<<<AG, blk, 0, stream>>>(T1 + 0, T1 + 256, T1 + 512,
                                             rowptr + 0 * NP1, col + 0 * (size_t)N_EDGES,
                                             proj1, proj1, rpe_s + 12, 1, cat1 + 0, 1536);
        // cross 1<-2: attn(k21, q12, v21, graph21)
        attn3_kernel<<<AG, blk, 0, stream>>>(T1 + 768, T2 + 256, T2 + 512,
                                             rowptr + 3 * NP1, col + 3 * (size_t)N_EDGES,
                                             nullptr, nullptr, rpe_s + 12, 0, cat1 + 256, 1536);
        // self 2: attn(k22, q22, v22, graph2, rpe2)
        attn3_kernel<<<AG, blk, 0, stream>>>(T2 + 768, T2 + 1024, T2 + 1280,
                                             rowptr + 1 * NP1, col + 1 * (size_t)N_EDGES,
                                             proj2, proj2, rpe_s + 12, 1, cat2 + 0, 1536);
        // cross 2<-1: attn(k12, q21, v12, graph12)
        attn3_kernel<<<AG, blk, 0, stream>>>(T2 + 0, T1 + 1024, T1 + 1280,
                                             rowptr + 2 * NP1, col + 2 * (size_t)N_EDGES,
                                             nullptr, nullptr, rpe_s + 12, 0, cat2 + 256, 1536);

        // proj: M=20000, N=256 (2 col-tiles), K=512
        gemm_pipe<<<dim3(2 * NROW * 2), blk, 0, stream>>>(
            cat1, cat2, 512, Wproj1t, Wproj2t, bproj1, bproj2, dF,
            out, 0, (size_t)N_NODES * 256, 256, dF, N_NODES, NROW, 2);
        return;
    }

    // ------------------------------------------------------------ fallback (round-1 proven path)
    u16* T = Told;
    const int GY = (N_NODES + 127) / 128;
    gemm_mfma<<<dim3(6, GY), blk, 0, stream>>>(feat1, 256, dF, Wqkv1t + 0 * 256,
                                               bqkv1, 0, dF, T, 0, 768, dZ, N_NODES, 768, 256);
    attn3_kernel<<<AG, blk, 0, stream>>>(T, T + 256, T + 512, rowptr + 0 * NP1, col + 0 * (size_t)N_EDGES,
                                         proj1, proj1, rpe_s + 12, 1, cat + 0, 768);
    gemm_mfma<<<dim3(2, GY), blk, 0, stream>>>(feat1, 256, dF, Wqkv1t + (size_t)768 * 256,
                                               bqkv1, 768, dF, T, 0, 768, dZ, N_NODES, 256, 256);
    gemm_mfma<<<dim3(4, GY), blk, 0, stream>>>(feat2, 256, dF, Wqkv2t + (size_t)256 * 256,
                                               bqkv2, 256, dF, T, 256, 768, dZ, N_NODES, 512, 256);
    attn3_kernel<<<AG, blk, 0, stream>>>(T, T + 256, T + 512, rowptr + 3 * NP1, col + 3 * (size_t)N_EDGES,
                                         nullptr, nullptr, rpe_s + 12, 0, cat + 256, 768);
    gemm_mfma<<<dim3(2, GY), blk, 0, stream>>>(cat, 512, dZ, Wproj1t,
                                               bproj1, 0, dF, out, 0, 256, dF, N_NODES, 256, 512);

    gemm_mfma<<<dim3(6, GY), blk, 0, stream>>>(feat2, 256, dF, Wqkv2t + (size_t)768 * 256,
                                               bqkv2, 768, dF, T, 0, 768, dZ, N_NODES, 768, 256);
    attn3_kernel<<<AG, blk, 0, stream>>>(T, T + 256, T + 512, rowptr + 1 * NP1, col + 1 * (size_t)N_EDGES,
                                         proj2, proj2, rpe_s + 12, 1, cat + 0, 768);
    gemm_mfma<<<dim3(2, GY), blk, 0, stream>>>(feat2, 256, dF, Wqkv2t + 0,
                                               bqkv2, 0, dF, T, 0, 768, dZ, N_NODES, 256, 256);
    gemm_mfma<<<dim3(4, GY), blk, 0, stream>>>(feat1, 256, dF, Wqkv1t + (size_t)1024 * 256,
                                               bqkv1, 1024, dF, T, 256, 768, dZ, N_NODES, 512, 256);
    attn3_kernel<<<AG, blk, 0, stream>>>(T, T + 256, T + 512, rowptr + 2 * NP1, col + 2 * (size_t)N_EDGES,
                                         nullptr, nullptr, rpe_s + 12, 0, cat + 256, 768);
    gemm_mfma<<<dim3(2, GY), blk, 0, stream>>>(cat, 512, dZ, Wproj2t,
                                               bproj2, 0, dF, out, (size_t)N_NODES * 256, 256, dF,
                                               N_NODES, 256, 512);
}